// Round 5
// baseline (421.935 us; speedup 1.0000x reference)
//
#include <hip/hip_runtime.h>

// MultiCellLSTM: B=4096 chains, H=64, T=512, 3 cell types by t%4 (0,2,1,2).
// R8: 8 waves per 16-row group (512 thr, 256 blocks, 1 block/CU) -> 2
// waves/SIMD to fill the ~45% latency stall R7 could not hide (1 wave/SIMD).
// Wave (p,e): p = h-slice (cols 16p..16p+15, all 4 gates), e = K-half AND
// activation-row-half:
//   e=0: G_partial = bias + x-MFMA + Wh[k=0:32]   (8 MFMA, has x/wix/bias)
//   e=1: G_partial = Wh[k=32:64]                  (4 MFMA, C=0)
// Partial exchange via f32 LDS (4x ds_write_b64 / 4x ds_read_b64, 2-way
// banked = free; 8 v_add); then e=0 activates D-rows 0,1 and e=1 rows 2,3
// (cx halves live per-wave). Two barriers/step. Aggregate per-SIMD issue
// unchanged (28 trans/step, now 14+14 on two co-resident waves); summation
// association bit-identical to R7: (bias+x+K0)+K1.
// __launch_bounds__(512,1): 1 BLOCK/CU (CUDA semantics; R5's (512,2) meant
// 2 blocks/CU -> 128-VGPR cap -> spill disaster). Cap 256, need ~200.
// Carried from R7: pre-packed x in LDS (xAf = bf16(x1)|bf16(x2)<<16, xBf =
// bf16(x3)), group-ahead lgkm-only prefetch; merged-rcp activation (7
// trans/cell); operand-swapped MFMA; bias as MFMA C-input; scale folded
// into weights; h write = cvt_pk + ds_write_b32; x-MFMA first per gate.
// Stale x2/x3 at off-phase steps are masked by zero weight columns.

typedef __attribute__((ext_vector_type(8))) short short8v;
typedef __attribute__((ext_vector_type(4))) float float4v;
typedef __attribute__((ext_vector_type(2))) float float2v;
typedef __attribute__((ext_vector_type(4))) unsigned int uint4v;

template <int N> struct IC { static constexpr int value = N; };

#define AST 72    // shorts per A row: 64 hx + 8 pad; 16B-aligned frags
#define XSA 516   // dwords per xA row (512+4 pad)
#define XSB 129   // dwords per xB row (128+1 pad)

#if __has_builtin(__builtin_amdgcn_exp2f)
#define EXP2F(x) __builtin_amdgcn_exp2f(x)
#else
#define EXP2F(x) exp2f(x)
#endif
#if __has_builtin(__builtin_amdgcn_rcpf)
#define RCPF(x) __builtin_amdgcn_rcpf(x)
#else
#define RCPF(x) (1.0f / (x))
#endif

#define NL2E -1.4426950408889634f   // -log2(e)
#define NL2E2 -2.8853900817779268f  // -2*log2(e)

__device__ __forceinline__ short f2bf(float f) {
  union { float f; unsigned u; } v; v.f = f;
  unsigned r = v.u + 0x7FFFu + ((v.u >> 16) & 1u);  // RNE
  return (short)(r >> 16);
}
__device__ __forceinline__ float bf2f(short h) {
  union { float f; unsigned u; } v;
  v.u = ((unsigned)(unsigned short)h) << 16;
  return v.f;
}
// pack two f32 -> two bf16 (RNE) in one instr: lo | hi<<16
__device__ __forceinline__ unsigned cvt_pk_bf16(float lo, float hi) {
  unsigned r;
  asm("v_cvt_pk_bf16_f32 %0, %1, %2" : "=v"(r) : "v"(lo), "v"(hi));
  return r;
}
// act on pre-scaled y: sigmoid(x) = rcp(1+exp2(y)), y = x*NL2E
__device__ __forceinline__ float rcp1p(float y) {
  return RCPF(1.0f + EXP2F(y));
}
__device__ __forceinline__ float fsig(float x) { return rcp1p(x * NL2E); }

__global__ __launch_bounds__(512, 1) void mlstm_kernel(
    const float* __restrict__ x1, const float* __restrict__ x2,
    const float* __restrict__ x3,
    const float* __restrict__ Wi3, const float* __restrict__ Wh3,
    const float* __restrict__ bi3, const float* __restrict__ bh3,
    const float* __restrict__ Wi2, const float* __restrict__ Wh2,
    const float* __restrict__ bi2, const float* __restrict__ bh2,
    const float* __restrict__ Wi1, const float* __restrict__ Wh1,
    const float* __restrict__ bi1, const float* __restrict__ bh1,
    const float* __restrict__ Wout, const float* __restrict__ bout,
    float* __restrict__ out) {
  __shared__ __attribute__((aligned(16))) short Ab0[16 * AST];
  __shared__ __attribute__((aligned(16))) short Ab1[16 * AST];
  __shared__ __attribute__((aligned(16))) unsigned xAf[16 * XSA];
  __shared__ __attribute__((aligned(16))) unsigned xBf[16 * XSB];
  __shared__ __attribute__((aligned(16))) float Pex[4][2][4][128];

  const int tid = threadIdx.x;  // 0..511
  const int wv = tid >> 6;      // wave 0..7
  const int p = wv & 3;         // h-col slice 0..3
  const int e = wv >> 2;        // K-half / row-half 0..1
  const int lane = tid & 63;
  const int q = lane >> 4;
  const int c = lane & 15;
  const int R0 = blockIdx.x << 4;

  // ---- preload x into LDS, pre-packed as a2 dwords ----
  for (int idx = tid; idx < 16 * 256; idx += 512) {
    int m = idx >> 8, tp = idx & 255;
    float2v v1 = *(const float2v*)(x1 + (size_t)(R0 + m) * 512 + 2 * tp);
    float v2 = x2[(size_t)(R0 + m) * 256 + tp];
    xAf[m * XSA + 2 * tp] = cvt_pk_bf16(v1[0], v2);
    xAf[m * XSA + 2 * tp + 1] = cvt_pk_bf16(v1[1], v2);
  }
  for (int idx = tid; idx < 16 * 128; idx += 512) {
    int m = idx >> 7, tt = idx & 127;
    xBf[m * XSB + tt] = cvt_pk_bf16(x3[(size_t)(R0 + m) * 128 + tt], 0.0f);
  }
  // ---- A buffers: hx(t=0) = 0 ----
  for (int idx = tid; idx < 16 * AST; idx += 512) {
    Ab0[idx] = 0;
    Ab1[idx] = 0;
  }

  // ---- pack scaled weight fragments ----
  // whs[ty][g]: this wave's K-half frag: elem j = s_g*Wh[n][e*32+q*8+j],
  //   n = g*64+16p+c  (swapped-mfma "A" operand)
  // wix/bias4: used by e=0 only (bias: elem r = s_g*(bi+bh)[g*64+16p+4q+r])
  short8v whs[3][4];
  short8v wix[3][4];
  float4v bias4[3][4];
  {
    const float* WhA[3] = {Wh3, Wh2, Wh1};
    const float* WiA[3] = {Wi3, Wi2, Wi1};
    const float* biA[3] = {bi3, bi2, bi1};
    const float* bhA[3] = {bh3, bh2, bh1};
    const int wdt[3] = {3, 2, 1};
#pragma unroll
    for (int ty = 0; ty < 3; ++ty) {
#pragma unroll
      for (int g = 0; g < 4; ++g) {
        const float sg = (g == 2) ? NL2E2 : NL2E;
        const int n = g * 64 + 16 * p + c;
        short8v v;
#pragma unroll
        for (int j = 0; j < 8; ++j)
          v[j] = f2bf(sg * WhA[ty][n * 64 + e * 32 + q * 8 + j]);
        whs[ty][g] = v;
        short8v v2 = {0, 0, 0, 0, 0, 0, 0, 0};
        if (e == 0 && q == 0) {
#pragma unroll
          for (int j = 0; j < 3; ++j)
            if (j < wdt[ty]) v2[j] = f2bf(sg * WiA[ty][n * wdt[ty] + j]);
        }
        wix[ty][g] = v2;
        float4v bv;
#pragma unroll
        for (int r = 0; r < 4; ++r) {
          const int nd = g * 64 + 16 * p + 4 * q + r;
          bv[r] = sg * (biA[ty][nd] + bhA[ty][nd]);
        }
        bias4[ty][g] = bv;
      }
    }
  }

  // addressing
  const int afo = c * AST + q * 8 + e * 32;       // hx frag: k-half e
  const int hwo = c * AST + 16 * p + 4 * q + 2 * e;  // h write: 2 cols (b32)
  float* pwr = &Pex[p][e][0][2 * lane];           // outgoing partial base
  const float* prd = &Pex[p][1 - e][0][2 * lane]; // incoming partial base
  const int xao = c * XSA;
  const int xbo = c * XSB;

  __syncthreads();

  float cx0 = 0.f, cx1 = 0.f;  // cell state: row c, h-cols 16p+4q+2e+{0,1}

  auto stepf = [&](auto tyc, unsigned dS, unsigned dx3, const short* rbuf,
                   short* wbuf) {
    constexpr int TY = decltype(tyc)::value;
    short8v ah = *(const short8v*)(rbuf + afo);

    float4v acc[4];
    if (e == 0) {
      // x-MFMA first (register operands) overlaps the ah ds_read latency
      uint4v au = {dS, dx3, 0u, 0u};
      short8v a2 = __builtin_bit_cast(short8v, au);
#pragma unroll
      for (int g = 0; g < 4; ++g) {
        float4v z = bias4[TY][g];
        z = __builtin_amdgcn_mfma_f32_16x16x32_bf16(wix[TY][g], a2, z, 0, 0, 0);
        z = __builtin_amdgcn_mfma_f32_16x16x32_bf16(whs[TY][g], ah, z, 0, 0, 0);
        acc[g] = z;
      }
    } else {
      const float4v zz = {0.f, 0.f, 0.f, 0.f};
#pragma unroll
      for (int g = 0; g < 4; ++g)
        acc[g] = __builtin_amdgcn_mfma_f32_16x16x32_bf16(whs[TY][g], ah, zz,
                                                         0, 0, 0);
    }

    // send the PARTNER's row-half (consecutive acc elems -> ds_write_b64)
    if (e == 0) {
#pragma unroll
      for (int g = 0; g < 4; ++g) {
        float2v o = {acc[g][2], acc[g][3]};
        *(float2v*)(pwr + g * 128) = o;
      }
    } else {
#pragma unroll
      for (int g = 0; g < 4; ++g) {
        float2v o = {acc[g][0], acc[g][1]};
        *(float2v*)(pwr + g * 128) = o;
      }
    }
    __syncthreads();  // barrier 1: partials visible

    // combine: my rows = acc[2e+u] + partner partial
    float G[4][2];
    if (e == 0) {
#pragma unroll
      for (int g = 0; g < 4; ++g) {
        float2v pg = *(const float2v*)(prd + g * 128);
        G[g][0] = acc[g][0] + pg[0];
        G[g][1] = acc[g][1] + pg[1];
      }
    } else {
#pragma unroll
      for (int g = 0; g < 4; ++g) {
        float2v pg = *(const float2v*)(prd + g * 128);
        G[g][0] = acc[g][2] + pg[0];
        G[g][1] = acc[g][3] + pg[1];
      }
    }

    float h2[2];
#pragma unroll
    for (int u = 0; u < 2; ++u) {
      float e0v = EXP2F(G[0][u]);
      float e1v = EXP2F(G[1][u]);
      float e2v = EXP2F(__builtin_fminf(G[2][u], 60.0f));
      float e3v = EXP2F(G[3][u]);
      float a = 1.0f + e0v, b = 1.0f + e1v, g2 = 1.0f + e2v;
      float ag = a * g2;
      float Rr = RCPF(ag * b);
      float cxu = u ? cx1 : cx0;
      float ncx = __builtin_fmaf(cxu, ag, (1.0f - e2v) * b) * Rr;
      if (u) cx1 = ncx; else cx0 = ncx;
      float e4v = EXP2F(__builtin_fminf(ncx * NL2E2, 60.0f));
      h2[u] = (1.0f - e4v) * RCPF((1.0f + e3v) * (1.0f + e4v));
    }
    *(unsigned*)(wbuf + hwo) = cvt_pk_bf16(h2[0], h2[1]);
    __syncthreads();  // barrier 2: hx(t+1) visible
  };

  // x dwords for group t4=0 (e=0 waves only; e=1 never touches x)
  uint4v xd = {0u, 0u, 0u, 0u};
  unsigned xw = 0u;
  if (e == 0) {
    xd = *(const uint4v*)(xAf + xao);
    xw = xBf[xbo];
  }

  // t%4 -> type: 0->0, 1->2, 2->1, 3->2
  for (int t4 = 0; t4 < 512; t4 += 4) {
    stepf(IC<0>{}, xd[0], xw, Ab0, Ab1);
    uint4v xdn = xd;
    unsigned xwn = xw;
    if (e == 0) {  // lgkm-only prefetch, hidden by a full step
      int tp = (t4 + 4 > 508) ? 508 : (t4 + 4);
      xdn = *(const uint4v*)(xAf + xao + tp);
      xwn = xBf[xbo + (tp >> 2)];
    }
    stepf(IC<2>{}, xd[1], xw, Ab1, Ab0);
    stepf(IC<1>{}, xd[2], xw, Ab0, Ab1);
    stepf(IC<2>{}, xd[3], xw, Ab1, Ab0);
    xd = xdn;
    xw = xwn;
  }
  // final hx (after 512 steps) is in Ab0

  if (tid < 16) {
    float s = bout[0];
    const short* hr = Ab0 + tid * AST;
#pragma unroll
    for (int k = 0; k < 64; ++k)
      s = __builtin_fmaf(bf2f(hr[k]), Wout[k], s);
    out[R0 + tid] = fsig(s);
  }
}

extern "C" void kernel_launch(void* const* d_in, const int* in_sizes, int n_in,
                              void* d_out, int out_size, void* d_ws,
                              size_t ws_size, hipStream_t stream) {
  const float* x1 = (const float*)d_in[0];
  const float* x2 = (const float*)d_in[1];
  const float* x3 = (const float*)d_in[2];
  const float* Wi3 = (const float*)d_in[3];
  const float* Wh3 = (const float*)d_in[4];
  const float* bi3 = (const float*)d_in[5];
  const float* bh3 = (const float*)d_in[6];
  const float* Wi2 = (const float*)d_in[7];
  const float* Wh2 = (const float*)d_in[8];
  const float* bi2 = (const float*)d_in[9];
  const float* bh2 = (const float*)d_in[10];
  const float* Wi1 = (const float*)d_in[11];
  const float* Wh1 = (const float*)d_in[12];
  const float* bi1 = (const float*)d_in[13];
  const float* bh1 = (const float*)d_in[14];
  const float* Wout = (const float*)d_in[15];
  const float* bout = (const float*)d_in[16];
  float* out = (float*)d_out;

  hipLaunchKernelGGL(mlstm_kernel, dim3(256), dim3(512), 0, stream,
                     x1, x2, x3, Wi3, Wh3, bi3, bh3, Wi2, Wh2, bi2, bh2,
                     Wi1, Wh1, bi1, bh1, Wout, bout, out);
}

// Round 8
// 306.306 us; speedup vs baseline: 1.3775x; 1.3775x over previous
//
#include <hip/hip_runtime.h>

// MultiCellLSTM: B=4096 chains, H=64, T=512, 3 cell types by t%4 (0,2,1,2).
// R9 (2nd resubmit; rounds 6-7 hit infra failures — GPUAcquisitionTimeout,
// then "container failed twice" — kernel has never executed).
// R7 skeleton (256 thr / 4 waves / 256 blocks; 1 wave/SIMD is STRUCTURAL:
// R5 showed independent-group splitting halves CU count; R8 showed intra-group
// splitting adds a serializing mid-step exchange). Issue/critical-path cuts:
//  - cross-cell rcp PAIRING (exact): R = rcp(D0*D1); 1/D0 = R*D1. Applied to
//    both the ncx-rcp and the h-rcp: 8 -> 4 rcps/step (-64cy issue, +24cy mul).
//    Overflow safety: clamp e2-arg at 30, e4-arg at 36 (paired products
//    < 2^120; tanh saturation limits stay exact).
//  - x-MFMA+bias HOIST: next step's zx[g] = mfma(wix[tyn], a2_next, bias[tyn])
//    issued during current activation (MFMA pipe idle there) -> only 8 MFMAs
//    on the post-barrier critical path; association unchanged (bit-identical).
// Carried from R7: pre-packed x in LDS (xAf = bf16(x1)|bf16(x2)<<16, xBf =
// bf16(x3)), group-ahead lgkm-only prefetch; operand-swapped MFMA (D=W.hx^T);
// activation scale folded into weights (act via exp2/rcp); h write = 2x
// cvt_pk + ds_write_b64; ONE barrier/step.
// Stale x2/x3 at off-phase steps are masked by zero weight columns.

typedef __attribute__((ext_vector_type(8))) short short8v;
typedef __attribute__((ext_vector_type(4))) float float4v;
typedef __attribute__((ext_vector_type(2))) float float2v;
typedef __attribute__((ext_vector_type(4))) unsigned int uint4v;
typedef __attribute__((ext_vector_type(2))) unsigned int uint2v;

template <int N> struct IC { static constexpr int value = N; };

#define AST 72    // shorts per A row: 64 hx + 8 pad; 16B-aligned frags
#define XSA 516   // dwords per xA row (512+4 pad)
#define XSB 129   // dwords per xB row (128+1 pad)

#if __has_builtin(__builtin_amdgcn_exp2f)
#define EXP2F(x) __builtin_amdgcn_exp2f(x)
#else
#define EXP2F(x) exp2f(x)
#endif
#if __has_builtin(__builtin_amdgcn_rcpf)
#define RCPF(x) __builtin_amdgcn_rcpf(x)
#else
#define RCPF(x) (1.0f / (x))
#endif

#define NL2E -1.4426950408889634f   // -log2(e)
#define NL2E2 -2.8853900817779268f  // -2*log2(e)

__device__ __forceinline__ short f2bf(float f) {
  union { float f; unsigned u; } v; v.f = f;
  unsigned r = v.u + 0x7FFFu + ((v.u >> 16) & 1u);  // RNE
  return (short)(r >> 16);
}
__device__ __forceinline__ float bf2f(short h) {
  union { float f; unsigned u; } v;
  v.u = ((unsigned)(unsigned short)h) << 16;
  return v.f;
}
// pack two f32 -> two bf16 (RNE) in one instr: lo | hi<<16
__device__ __forceinline__ unsigned cvt_pk_bf16(float lo, float hi) {
  unsigned r;
  asm("v_cvt_pk_bf16_f32 %0, %1, %2" : "=v"(r) : "v"(lo), "v"(hi));
  return r;
}
// act on pre-scaled y: sigmoid(x) = rcp(1+exp2(y)), y = x*NL2E
__device__ __forceinline__ float rcp1p(float y) {
  return RCPF(1.0f + EXP2F(y));
}
__device__ __forceinline__ float fsig(float x) { return rcp1p(x * NL2E); }

__global__ __launch_bounds__(256, 1) void mlstm_kernel(
    const float* __restrict__ x1, const float* __restrict__ x2,
    const float* __restrict__ x3,
    const float* __restrict__ Wi3, const float* __restrict__ Wh3,
    const float* __restrict__ bi3, const float* __restrict__ bh3,
    const float* __restrict__ Wi2, const float* __restrict__ Wh2,
    const float* __restrict__ bi2, const float* __restrict__ bh2,
    const float* __restrict__ Wi1, const float* __restrict__ Wh1,
    const float* __restrict__ bi1, const float* __restrict__ bh1,
    const float* __restrict__ Wout, const float* __restrict__ bout,
    float* __restrict__ out) {
  __shared__ __attribute__((aligned(16))) short Ab0[16 * AST];
  __shared__ __attribute__((aligned(16))) short Ab1[16 * AST];
  __shared__ __attribute__((aligned(16))) unsigned xAf[16 * XSA];
  __shared__ __attribute__((aligned(16))) unsigned xBf[16 * XSB];

  const int tid = threadIdx.x;  // 0..255
  const int w = tid >> 6;       // wave = h-col slice 0..3
  const int lane = tid & 63;
  const int q = lane >> 4;
  const int c = lane & 15;
  const int R0 = blockIdx.x << 4;

  // ---- preload x into LDS, pre-packed as a2 dwords ----
  for (int idx = tid; idx < 16 * 256; idx += 256) {
    int m = idx >> 8, tp = idx & 255;
    float2v v1 = *(const float2v*)(x1 + (size_t)(R0 + m) * 512 + 2 * tp);
    float v2 = x2[(size_t)(R0 + m) * 256 + tp];
    xAf[m * XSA + 2 * tp] = cvt_pk_bf16(v1[0], v2);
    xAf[m * XSA + 2 * tp + 1] = cvt_pk_bf16(v1[1], v2);
  }
  for (int idx = tid; idx < 16 * 128; idx += 256) {
    int m = idx >> 7, tt = idx & 127;
    xBf[m * XSB + tt] = cvt_pk_bf16(x3[(size_t)(R0 + m) * 128 + tt], 0.0f);
  }
  // ---- A buffers: hx(t=0) = 0 ----
  for (int idx = tid; idx < 16 * AST; idx += 256) {
    Ab0[idx] = 0;
    Ab1[idx] = 0;
  }

  // ---- pack scaled weight fragments (per wave: tiles g=0..3) ----
  short8v whs[3][4][2];
  short8v wix[3][4];
  float4v bias4[3][4];
  {
    const float* WhA[3] = {Wh3, Wh2, Wh1};
    const float* WiA[3] = {Wi3, Wi2, Wi1};
    const float* biA[3] = {bi3, bi2, bi1};
    const float* bhA[3] = {bh3, bh2, bh1};
    const int wdt[3] = {3, 2, 1};
#pragma unroll
    for (int ty = 0; ty < 3; ++ty) {
#pragma unroll
      for (int g = 0; g < 4; ++g) {
        const float sg = (g == 2) ? NL2E2 : NL2E;
        const int n = g * 64 + 16 * w + c;
#pragma unroll
        for (int kf = 0; kf < 2; ++kf) {
          short8v v;
#pragma unroll
          for (int j = 0; j < 8; ++j)
            v[j] = f2bf(sg * WhA[ty][n * 64 + kf * 32 + q * 8 + j]);
          whs[ty][g][kf] = v;
        }
        short8v v2 = {0, 0, 0, 0, 0, 0, 0, 0};
        if (q == 0) {
#pragma unroll
          for (int j = 0; j < 3; ++j)
            if (j < wdt[ty]) v2[j] = f2bf(sg * WiA[ty][n * wdt[ty] + j]);
        }
        wix[ty][g] = v2;
        float4v bv;
#pragma unroll
        for (int r = 0; r < 4; ++r) {
          const int nd = g * 64 + 16 * w + 4 * q + r;  // D-row = gate col
          bv[r] = sg * (biA[ty][nd] + bhA[ty][nd]);
        }
        bias4[ty][g] = bv;
      }
    }
  }

  // addressing
  const int afo = c * AST + q * 8;          // hx frag: n=c(row), k=q*8+j
  const int hwo = c * AST + 16 * w + 4 * q; // h write: row c, cols 16w+4q+r
  const int xao = c * XSA;
  const int xbo = c * XSB;

  __syncthreads();

  float cx[4] = {0.f, 0.f, 0.f, 0.f};  // cell state: row c, hcol 16w+4q+r

  // zx[g] = bias + x-part of gates, computed ONE STEP AHEAD (ping-pong A/B)
  float4v zxA[4], zxB[4];

  auto stepf = [&](auto tyc, auto tync, unsigned dSn, unsigned dx3n,
                   const short* rbuf, short* wbuf, float4v (&zin)[4],
                   float4v (&zout)[4]) {
    constexpr int TY = decltype(tyc)::value;
    constexpr int TYN = decltype(tync)::value;
    short8v a0 = *(const short8v*)(rbuf + afo);
    short8v a1 = *(const short8v*)(rbuf + afo + 32);

    float4v acc[4];
#pragma unroll
    for (int g = 0; g < 4; ++g) {
      float4v z =
          __builtin_amdgcn_mfma_f32_16x16x32_bf16(whs[TY][g][0], a0, zin[g], 0, 0, 0);
      acc[g] =
          __builtin_amdgcn_mfma_f32_16x16x32_bf16(whs[TY][g][1], a1, z, 0, 0, 0);
    }

    // hoisted x-part for NEXT step (register operands; MFMA pipe is idle
    // during activation). Same association as before -> bit-identical.
    uint4v aun = {dSn, dx3n, 0u, 0u};
    short8v a2n = __builtin_bit_cast(short8v, aun);
#pragma unroll
    for (int g = 0; g < 4; ++g)
      zout[g] = __builtin_amdgcn_mfma_f32_16x16x32_bf16(wix[TYN][g], a2n,
                                                        bias4[TYN][g], 0, 0, 0);

    // activation: cells paired (r0,r1) to share each rcp across two cells.
    float h4[4];
#pragma unroll
    for (int pr = 0; pr < 2; ++pr) {
      const int r0 = 2 * pr, r1 = 2 * pr + 1;
      // e = exp2 of pre-scaled gates: e^-i, e^-f, e^-2g (clamped), e^-o
      float e0a = EXP2F(acc[0][r0]), e0b = EXP2F(acc[0][r1]);
      float e1a = EXP2F(acc[1][r0]), e1b = EXP2F(acc[1][r1]);
      float e2a = EXP2F(__builtin_fminf(acc[2][r0], 30.0f));
      float e2b = EXP2F(__builtin_fminf(acc[2][r1], 30.0f));
      float aa = 1.0f + e0a, ba = 1.0f + e1a, ga = 1.0f + e2a;
      float ab_ = 1.0f + e0b, bb = 1.0f + e1b, gb = 1.0f + e2b;
      float aga = aa * ga, agb = ab_ * gb;
      float Da = aga * ba, Db = agb * bb;
      float Rp = RCPF(Da * Db);  // one rcp for two cells' phase-1
      float Ra = Rp * Db, Rb = Rp * Da;
      float nca = __builtin_fmaf(cx[r0], aga, (1.0f - e2a) * ba) * Ra;
      float ncb = __builtin_fmaf(cx[r1], agb, (1.0f - e2b) * bb) * Rb;
      cx[r0] = nca;
      cx[r1] = ncb;
      float e3a = EXP2F(acc[3][r0]), e3b = EXP2F(acc[3][r1]);
      float e4a = EXP2F(__builtin_fminf(nca * NL2E2, 36.0f));
      float e4b = EXP2F(__builtin_fminf(ncb * NL2E2, 36.0f));
      float D2a = (1.0f + e3a) * (1.0f + e4a);
      float D2b = (1.0f + e3b) * (1.0f + e4b);
      float R2 = RCPF(D2a * D2b);  // one rcp for two cells' phase-2
      h4[r0] = (1.0f - e4a) * (R2 * D2b);
      h4[r1] = (1.0f - e4b) * (R2 * D2a);
    }
    uint2v pk;
    pk[0] = cvt_pk_bf16(h4[0], h4[1]);
    pk[1] = cvt_pk_bf16(h4[2], h4[3]);
    *(uint2v*)(wbuf + hwo) = pk;  // one ds_write_b64
    __syncthreads();
  };

  // x dwords for group t4=0
  uint4v xd = *(const uint4v*)(xAf + xao);
  unsigned xw = xBf[xbo];

  // prologue: zx for t=0 (type 0)
  {
    uint4v au = {xd[0], xw, 0u, 0u};
    short8v a2 = __builtin_bit_cast(short8v, au);
#pragma unroll
    for (int g = 0; g < 4; ++g)
      zxA[g] = __builtin_amdgcn_mfma_f32_16x16x32_bf16(wix[0][g], a2,
                                                       bias4[0][g], 0, 0, 0);
  }

  // t%4 -> type: 0->0, 1->2, 2->1, 3->2; each step also builds next step's zx
  for (int t4 = 0; t4 < 512; t4 += 4) {
    stepf(IC<0>{}, IC<2>{}, xd[1], xw, Ab0, Ab1, zxA, zxB);
    // prefetch next group's x from LDS (clamped on last iter; unused)
    int tp = (t4 + 4 > 508) ? 508 : (t4 + 4);
    uint4v xdn = *(const uint4v*)(xAf + xao + tp);
    unsigned xwn = xBf[xbo + (tp >> 2)];
    stepf(IC<2>{}, IC<1>{}, xd[2], xw, Ab1, Ab0, zxB, zxA);
    stepf(IC<1>{}, IC<2>{}, xd[3], xw, Ab0, Ab1, zxA, zxB);
    stepf(IC<2>{}, IC<0>{}, xdn[0], xwn, Ab1, Ab0, zxB, zxA);
    xd = xdn;
    xw = xwn;
  }
  // final hx (after 512 steps) is in Ab0

  if (tid < 16) {
    float s = bout[0];
    const short* hr = Ab0 + tid * AST;
#pragma unroll
    for (int k = 0; k < 64; ++k)
      s = __builtin_fmaf(bf2f(hr[k]), Wout[k], s);
    out[R0 + tid] = fsig(s);
  }
}

extern "C" void kernel_launch(void* const* d_in, const int* in_sizes, int n_in,
                              void* d_out, int out_size, void* d_ws,
                              size_t ws_size, hipStream_t stream) {
  const float* x1 = (const float*)d_in[0];
  const float* x2 = (const float*)d_in[1];
  const float* x3 = (const float*)d_in[2];
  const float* Wi3 = (const float*)d_in[3];
  const float* Wh3 = (const float*)d_in[4];
  const float* bi3 = (const float*)d_in[5];
  const float* bh3 = (const float*)d_in[6];
  const float* Wi2 = (const float*)d_in[7];
  const float* Wh2 = (const float*)d_in[8];
  const float* bi2 = (const float*)d_in[9];
  const float* bh2 = (const float*)d_in[10];
  const float* Wi1 = (const float*)d_in[11];
  const float* Wh1 = (const float*)d_in[12];
  const float* bi1 = (const float*)d_in[13];
  const float* bh1 = (const float*)d_in[14];
  const float* Wout = (const float*)d_in[15];
  const float* bout = (const float*)d_in[16];
  float* out = (float*)d_out;

  hipLaunchKernelGGL(mlstm_kernel, dim3(256), dim3(256), 0, stream,
                     x1, x2, x3, Wi3, Wh3, bi3, bh3, Wi2, Wh2, bi2, bh2,
                     Wi1, Wh1, bi1, bh1, Wout, bout, out);
}

// Round 9
// 301.062 us; speedup vs baseline: 1.4015x; 1.0174x over previous
//
#include <hip/hip_runtime.h>

// MultiCellLSTM: B=4096 chains, H=64, T=512, 3 cell types by t%4 (0,2,1,2).
// R10: disentangle R9's bundle. R9 (246.5us) REGRESSED vs R7 (237.8us):
// cross-cell rcp pairing coupled the 4 independent per-cell activation
// chains into 2 (at 1 wave/SIMD, intra-wave ILP is the only latency cover
// -> chain coupling exposed ~70cy > ~50cy issue saved). R10 = R7's exact
// activation (7 trans/cell, 4 INDEPENDENT chains, clamps at 60) + keep only
// R9's x-MFMA+bias HOIST (proven correct there): next step's zx[g] =
// mfma(wix, a2_next, bias) issued during current activation -> 8 (not 12)
// MFMAs between barrier and activation start; association unchanged.
// Also: MFMA gate order {f,g,i,o} so gates feeding the activation chain
// head (e1,e2) complete first, o-gate (needed last) completes last.
// Carried from R7: 256 thr / 4 waves / 256 blocks (1 wave/SIMD structural:
// R5 independent-split halves CUs, R8 intra-split serializes); pre-packed x
// in LDS (xAf = bf16(x1)|bf16(x2)<<16, xBf = bf16(x3)), group-ahead
// lgkm-only prefetch; operand-swapped MFMA (D=W.hx^T); activation scale
// folded into weights (act via exp2/rcp); h write = 2x cvt_pk +
// ds_write_b64; ONE barrier/step.
// Stale x2/x3 at off-phase steps are masked by zero weight columns.

typedef __attribute__((ext_vector_type(8))) short short8v;
typedef __attribute__((ext_vector_type(4))) float float4v;
typedef __attribute__((ext_vector_type(2))) float float2v;
typedef __attribute__((ext_vector_type(4))) unsigned int uint4v;
typedef __attribute__((ext_vector_type(2))) unsigned int uint2v;

template <int N> struct IC { static constexpr int value = N; };

#define AST 72    // shorts per A row: 64 hx + 8 pad; 16B-aligned frags
#define XSA 516   // dwords per xA row (512+4 pad)
#define XSB 129   // dwords per xB row (128+1 pad)

#if __has_builtin(__builtin_amdgcn_exp2f)
#define EXP2F(x) __builtin_amdgcn_exp2f(x)
#else
#define EXP2F(x) exp2f(x)
#endif
#if __has_builtin(__builtin_amdgcn_rcpf)
#define RCPF(x) __builtin_amdgcn_rcpf(x)
#else
#define RCPF(x) (1.0f / (x))
#endif

#define NL2E -1.4426950408889634f   // -log2(e)
#define NL2E2 -2.8853900817779268f  // -2*log2(e)

__device__ __forceinline__ short f2bf(float f) {
  union { float f; unsigned u; } v; v.f = f;
  unsigned r = v.u + 0x7FFFu + ((v.u >> 16) & 1u);  // RNE
  return (short)(r >> 16);
}
__device__ __forceinline__ float bf2f(short h) {
  union { float f; unsigned u; } v;
  v.u = ((unsigned)(unsigned short)h) << 16;
  return v.f;
}
// pack two f32 -> two bf16 (RNE) in one instr: lo | hi<<16
__device__ __forceinline__ unsigned cvt_pk_bf16(float lo, float hi) {
  unsigned r;
  asm("v_cvt_pk_bf16_f32 %0, %1, %2" : "=v"(r) : "v"(lo), "v"(hi));
  return r;
}
// act on pre-scaled y: sigmoid(x) = rcp(1+exp2(y)), y = x*NL2E
__device__ __forceinline__ float rcp1p(float y) {
  return RCPF(1.0f + EXP2F(y));
}
__device__ __forceinline__ float fsig(float x) { return rcp1p(x * NL2E); }

__global__ __launch_bounds__(256, 1) void mlstm_kernel(
    const float* __restrict__ x1, const float* __restrict__ x2,
    const float* __restrict__ x3,
    const float* __restrict__ Wi3, const float* __restrict__ Wh3,
    const float* __restrict__ bi3, const float* __restrict__ bh3,
    const float* __restrict__ Wi2, const float* __restrict__ Wh2,
    const float* __restrict__ bi2, const float* __restrict__ bh2,
    const float* __restrict__ Wi1, const float* __restrict__ Wh1,
    const float* __restrict__ bi1, const float* __restrict__ bh1,
    const float* __restrict__ Wout, const float* __restrict__ bout,
    float* __restrict__ out) {
  __shared__ __attribute__((aligned(16))) short Ab0[16 * AST];
  __shared__ __attribute__((aligned(16))) short Ab1[16 * AST];
  __shared__ __attribute__((aligned(16))) unsigned xAf[16 * XSA];
  __shared__ __attribute__((aligned(16))) unsigned xBf[16 * XSB];

  const int tid = threadIdx.x;  // 0..255
  const int w = tid >> 6;       // wave = h-col slice 0..3
  const int lane = tid & 63;
  const int q = lane >> 4;
  const int c = lane & 15;
  const int R0 = blockIdx.x << 4;

  // ---- preload x into LDS, pre-packed as a2 dwords ----
  for (int idx = tid; idx < 16 * 256; idx += 256) {
    int m = idx >> 8, tp = idx & 255;
    float2v v1 = *(const float2v*)(x1 + (size_t)(R0 + m) * 512 + 2 * tp);
    float v2 = x2[(size_t)(R0 + m) * 256 + tp];
    xAf[m * XSA + 2 * tp] = cvt_pk_bf16(v1[0], v2);
    xAf[m * XSA + 2 * tp + 1] = cvt_pk_bf16(v1[1], v2);
  }
  for (int idx = tid; idx < 16 * 128; idx += 256) {
    int m = idx >> 7, tt = idx & 127;
    xBf[m * XSB + tt] = cvt_pk_bf16(x3[(size_t)(R0 + m) * 128 + tt], 0.0f);
  }
  // ---- A buffers: hx(t=0) = 0 ----
  for (int idx = tid; idx < 16 * AST; idx += 256) {
    Ab0[idx] = 0;
    Ab1[idx] = 0;
  }

  // ---- pack scaled weight fragments (per wave: tiles g=0..3) ----
  short8v whs[3][4][2];
  short8v wix[3][4];
  float4v bias4[3][4];
  {
    const float* WhA[3] = {Wh3, Wh2, Wh1};
    const float* WiA[3] = {Wi3, Wi2, Wi1};
    const float* biA[3] = {bi3, bi2, bi1};
    const float* bhA[3] = {bh3, bh2, bh1};
    const int wdt[3] = {3, 2, 1};
#pragma unroll
    for (int ty = 0; ty < 3; ++ty) {
#pragma unroll
      for (int g = 0; g < 4; ++g) {
        const float sg = (g == 2) ? NL2E2 : NL2E;
        const int n = g * 64 + 16 * w + c;
#pragma unroll
        for (int kf = 0; kf < 2; ++kf) {
          short8v v;
#pragma unroll
          for (int j = 0; j < 8; ++j)
            v[j] = f2bf(sg * WhA[ty][n * 64 + kf * 32 + q * 8 + j]);
          whs[ty][g][kf] = v;
        }
        short8v v2 = {0, 0, 0, 0, 0, 0, 0, 0};
        if (q == 0) {
#pragma unroll
          for (int j = 0; j < 3; ++j)
            if (j < wdt[ty]) v2[j] = f2bf(sg * WiA[ty][n * wdt[ty] + j]);
        }
        wix[ty][g] = v2;
        float4v bv;
#pragma unroll
        for (int r = 0; r < 4; ++r) {
          const int nd = g * 64 + 16 * w + 4 * q + r;  // D-row = gate col
          bv[r] = sg * (biA[ty][nd] + bhA[ty][nd]);
        }
        bias4[ty][g] = bv;
      }
    }
  }

  // addressing
  const int afo = c * AST + q * 8;          // hx frag: n=c(row), k=q*8+j
  const int hwo = c * AST + 16 * w + 4 * q; // h write: row c, cols 16w+4q+r
  const int xao = c * XSA;
  const int xbo = c * XSB;

  __syncthreads();

  float cx[4] = {0.f, 0.f, 0.f, 0.f};  // cell state: row c, hcol 16w+4q+r

  // zx[g] = bias + x-part of gates, computed ONE STEP AHEAD (ping-pong A/B)
  float4v zxA[4], zxB[4];

  // gate completion order: f(1), g(2) feed the activation-chain head;
  // i(0) mid; o(3) is needed only at the end.
  const int GORD[4] = {1, 2, 0, 3};

  auto stepf = [&](auto tyc, auto tync, unsigned dSn, unsigned dx3n,
                   const short* rbuf, short* wbuf, float4v (&zin)[4],
                   float4v (&zout)[4]) {
    constexpr int TY = decltype(tyc)::value;
    constexpr int TYN = decltype(tync)::value;
    short8v a0 = *(const short8v*)(rbuf + afo);
    short8v a1 = *(const short8v*)(rbuf + afo + 32);

    float4v acc[4];
#pragma unroll
    for (int gi = 0; gi < 4; ++gi) {
      const int g = GORD[gi];
      float4v z =
          __builtin_amdgcn_mfma_f32_16x16x32_bf16(whs[TY][g][0], a0, zin[g], 0, 0, 0);
      acc[g] =
          __builtin_amdgcn_mfma_f32_16x16x32_bf16(whs[TY][g][1], a1, z, 0, 0, 0);
    }

    // hoisted x-part for NEXT step (register operands; MFMA pipe idle
    // during activation). Same association as R7 -> bit-identical.
    uint4v aun = {dSn, dx3n, 0u, 0u};
    short8v a2n = __builtin_bit_cast(short8v, aun);
#pragma unroll
    for (int g = 0; g < 4; ++g)
      zout[g] = __builtin_amdgcn_mfma_f32_16x16x32_bf16(wix[TYN][g], a2n,
                                                        bias4[TYN][g], 0, 0, 0);

    // activation: R7 form — 4 INDEPENDENT per-cell chains (ILP is the only
    // latency cover at 1 wave/SIMD; do NOT couple them).
    float h4[4];
#pragma unroll
    for (int r = 0; r < 4; ++r) {
      float e0 = EXP2F(acc[0][r]);
      float e1 = EXP2F(acc[1][r]);
      float e2 = EXP2F(__builtin_fminf(acc[2][r], 60.0f));
      float e3 = EXP2F(acc[3][r]);
      float a = 1.0f + e0, b = 1.0f + e1, g2 = 1.0f + e2;
      float ag = a * g2;
      float Rr = RCPF(ag * b);  // one rcp covers sig(f) and sig(i)*tanh(g)
      float ncx = __builtin_fmaf(cx[r], ag, (1.0f - e2) * b) * Rr;
      cx[r] = ncx;
      // sig(o)*tanh(ncx) = (1-e4) / ((1+e3)(1+e4)); clamp keeps exact
      // tanh->-1 saturation limit instead of inf*0 = NaN
      float e4 = EXP2F(__builtin_fminf(ncx * NL2E2, 60.0f));
      h4[r] = (1.0f - e4) * RCPF((1.0f + e3) * (1.0f + e4));
    }
    uint2v pk;
    pk[0] = cvt_pk_bf16(h4[0], h4[1]);
    pk[1] = cvt_pk_bf16(h4[2], h4[3]);
    *(uint2v*)(wbuf + hwo) = pk;  // one ds_write_b64
    __syncthreads();
  };

  // x dwords for group t4=0
  uint4v xd = *(const uint4v*)(xAf + xao);
  unsigned xw = xBf[xbo];

  // prologue: zx for t=0 (type 0)
  {
    uint4v au = {xd[0], xw, 0u, 0u};
    short8v a2 = __builtin_bit_cast(short8v, au);
#pragma unroll
    for (int g = 0; g < 4; ++g)
      zxA[g] = __builtin_amdgcn_mfma_f32_16x16x32_bf16(wix[0][g], a2,
                                                       bias4[0][g], 0, 0, 0);
  }

  // t%4 -> type: 0->0, 1->2, 2->1, 3->2; each step also builds next step's zx
  for (int t4 = 0; t4 < 512; t4 += 4) {
    stepf(IC<0>{}, IC<2>{}, xd[1], xw, Ab0, Ab1, zxA, zxB);
    // prefetch next group's x from LDS (clamped on last iter; unused)
    int tp = (t4 + 4 > 508) ? 508 : (t4 + 4);
    uint4v xdn = *(const uint4v*)(xAf + xao + tp);
    unsigned xwn = xBf[xbo + (tp >> 2)];
    stepf(IC<2>{}, IC<1>{}, xd[2], xw, Ab1, Ab0, zxB, zxA);
    stepf(IC<1>{}, IC<2>{}, xd[3], xw, Ab0, Ab1, zxA, zxB);
    stepf(IC<2>{}, IC<0>{}, xdn[0], xwn, Ab1, Ab0, zxB, zxA);
    xd = xdn;
    xw = xwn;
  }
  // final hx (after 512 steps) is in Ab0

  if (tid < 16) {
    float s = bout[0];
    const short* hr = Ab0 + tid * AST;
#pragma unroll
    for (int k = 0; k < 64; ++k)
      s = __builtin_fmaf(bf2f(hr[k]), Wout[k], s);
    out[R0 + tid] = fsig(s);
  }
}

extern "C" void kernel_launch(void* const* d_in, const int* in_sizes, int n_in,
                              void* d_out, int out_size, void* d_ws,
                              size_t ws_size, hipStream_t stream) {
  const float* x1 = (const float*)d_in[0];
  const float* x2 = (const float*)d_in[1];
  const float* x3 = (const float*)d_in[2];
  const float* Wi3 = (const float*)d_in[3];
  const float* Wh3 = (const float*)d_in[4];
  const float* bi3 = (const float*)d_in[5];
  const float* bh3 = (const float*)d_in[6];
  const float* Wi2 = (const float*)d_in[7];
  const float* Wh2 = (const float*)d_in[8];
  const float* bi2 = (const float*)d_in[9];
  const float* bh2 = (const float*)d_in[10];
  const float* Wi1 = (const float*)d_in[11];
  const float* Wh1 = (const float*)d_in[12];
  const float* bi1 = (const float*)d_in[13];
  const float* bh1 = (const float*)d_in[14];
  const float* Wout = (const float*)d_in[15];
  const float* bout = (const float*)d_in[16];
  float* out = (float*)d_out;

  hipLaunchKernelGGL(mlstm_kernel, dim3(256), dim3(256), 0, stream,
                     x1, x2, x3, Wi3, Wh3, bi3, bh3, Wi2, Wh2, bi2, bh2,
                     Wi1, Wh1, bi1, bh1, Wout, bout, out);
}